// Round 6
// baseline (396.102 us; speedup 1.0000x reference)
//
#include <hip/hip_runtime.h>
#include <hip/hip_bf16.h>
#include <hip/hip_cooperative_groups.h>

namespace cg = cooperative_groups;

// Sizes (fixed by the reference)
#define BI 64
#define BC 64
#define TCAP 64
#define D 1024
#define H 128
#define TIMG 36

// =================== single cooperative kernel: 1024 blocks x 256 ===================
__global__ __launch_bounds__(256, 4) void k_all(
    const float* __restrict__ img, const float* __restrict__ cap,
    const float* __restrict__ Wg1, const float* __restrict__ bg1,
    const float* __restrict__ Wg2, const float* __restrict__ bg2,
    const float* __restrict__ Wb1, const float* __restrict__ bb1,
    const float* __restrict__ Wb2, const float* __restrict__ bb2,
    float* __restrict__ repr, float* __restrict__ ivec,
    float* __restrict__ gam, float* __restrict__ bet,
    float* __restrict__ mu, float* __restrict__ istd,
    float* __restrict__ part, float* __restrict__ W1T,
    float* __restrict__ hid, float* __restrict__ out)
{
    cg::grid_group grid = cg::this_grid();
    __shared__ float smem[64 * 65];   // 16.6 KB, reused across phases
    const int blk = blockIdx.x, tid = threadIdx.x;
    const int lane = tid & 63, wave = tid >> 6;

    // ---------------- P1: img stats | cap partial stats | W1 transpose ----------------
    if (blk < 64) {
        int i = blk;
        const float4* base = (const float4*)(img + (size_t)i * TIMG * D);
        float4 s = {0.f, 0.f, 0.f, 0.f};
        for (int t = 0; t < TIMG; ++t) {
            float4 v = base[t * 256 + tid];
            s.x += v.x; s.y += v.y; s.z += v.z; s.w += v.w;
        }
        s.x *= (1.f / 36.f); s.y *= (1.f / 36.f); s.z *= (1.f / 36.f); s.w *= (1.f / 36.f);
        ((float4*)(repr + (size_t)i * D))[tid] = s;
        float local = s.x * s.x + s.y * s.y + s.z * s.z + s.w * s.w;
        for (int off = 32; off; off >>= 1) local += __shfl_xor(local, off);
        if (lane == 0) smem[wave] = local;
        __syncthreads();
        float inv = rsqrtf(smem[0] + smem[1] + smem[2] + smem[3]);
        float4 o = {s.x * inv, s.y * inv, s.z * inv, s.w * inv};
        ((float4*)(ivec + (size_t)i * D))[tid] = o;
    } else if (blk < 128) {
        int b = blk - 64;
        const float4* base = (const float4*)(cap + (size_t)b * TCAP * D);
        float4 s = {0.f, 0.f, 0.f, 0.f}, ss = {0.f, 0.f, 0.f, 0.f};
        for (int t = 0; t < TIMG; ++t) {
            float4 v = base[t * 256 + tid];
            s.x += v.x; s.y += v.y; s.z += v.z; s.w += v.w;
            ss.x = fmaf(v.x, v.x, ss.x); ss.y = fmaf(v.y, v.y, ss.y);
            ss.z = fmaf(v.z, v.z, ss.z); ss.w = fmaf(v.w, v.w, ss.w);
        }
        ((float4*)(part + b * 2048))[tid] = s;
        ((float4*)(part + b * 2048 + 1024))[tid] = ss;
    } else if (blk < 192) {
        float (*tile)[65] = (float (*)[65])smem;
        int idx = blk - 128;
        int bx = idx & 15, by = (idx >> 4) & 1, bz = idx >> 5;
        const float* W = bz ? Wb1 : Wg1;
        int d0 = bx * 64, c0 = by * 64;
#pragma unroll
        for (int k = 0; k < 16; ++k) {
            int dl = k * 4 + wave;
            tile[dl][lane] = W[(size_t)(d0 + dl) * H + c0 + lane];
        }
        __syncthreads();
#pragma unroll
        for (int k = 0; k < 16; ++k) {
            int cl = k * 4 + wave;
            W1T[(size_t)(bz * 128 + c0 + cl) * D + d0 + lane] = tile[lane][cl];
        }
    }
    grid.sync();

    // ---------------- P2: stat finalize (block 0) | hidden layer (blocks 4..1023) ----------------
    if (blk == 0) {
        const float4* p4 = (const float4*)part;
        float4 s = {0.f, 0.f, 0.f, 0.f}, q = {0.f, 0.f, 0.f, 0.f};
        for (int g = 0; g < BC; ++g) {
            float4 a4 = p4[g * 512 + tid];
            float4 b4 = p4[g * 512 + 256 + tid];
            s.x += a4.x; s.y += a4.y; s.z += a4.z; s.w += a4.w;
            q.x += b4.x; q.y += b4.y; q.z += b4.z; q.w += b4.w;
        }
        const float invN = 1.f / 2304.f;
        float4 m = {s.x * invN, s.y * invN, s.z * invN, s.w * invN};
        float4 v = {q.x * invN - m.x * m.x, q.y * invN - m.y * m.y,
                    q.z * invN - m.z * m.z, q.w * invN - m.w * m.w};
        ((float4*)mu)[tid] = m;
        float4 ist = {rsqrtf(v.x + 1e-5f), rsqrtf(v.y + 1e-5f),
                      rsqrtf(v.z + 1e-5f), rsqrtf(v.w + 1e-5f)};
        ((float4*)istd)[tid] = ist;
    } else if (blk >= 4) {
        int wg = (blk - 4) * 4 + wave;           // 4080 waves
        for (int tsk = wg; tsk < 16384; tsk += 4080) {
            int i = tsk >> 8, cc = tsk & 255;
            const float4* r4 = (const float4*)(repr + (size_t)i * D);
            const float4* w4 = (const float4*)(W1T + (size_t)cc * D);
            float acc = 0.f;
#pragma unroll
            for (int k = 0; k < 4; ++k) {
                float4 rv = r4[k * 64 + lane];
                float4 wv = w4[k * 64 + lane];
                acc = fmaf(rv.x, wv.x, acc);
                acc = fmaf(rv.y, wv.y, acc);
                acc = fmaf(rv.z, wv.z, acc);
                acc = fmaf(rv.w, wv.w, acc);
            }
            for (int off = 32; off; off >>= 1) acc += __shfl_xor(acc, off);
            if (lane == 0) {
                float b1v = (cc < 128) ? bg1[cc] : bb1[cc - 128];
                hid[tsk] = fmaxf(acc + b1v, 0.f);
            }
        }
    }
    grid.sync();

    // ---------------- P3: second MLP layer -> gam, bet (blocks 0..127) ----------------
    if (blk < 128) {
        int i = blk >> 1;
        int d2 = (blk & 1) * 256 + tid;
        float* h = smem;
        h[tid] = hid[i * 256 + tid];
        __syncthreads();
        float2 g = ((const float2*)bg2)[d2];
        float2 bv = ((const float2*)bb2)[d2];
#pragma unroll 4
        for (int hh = 0; hh < H; ++hh) {
            float2 wg = ((const float2*)(Wg2 + (size_t)hh * D))[d2];
            float2 wb = ((const float2*)(Wb2 + (size_t)hh * D))[d2];
            float hg = h[hh], hb = h[128 + hh];
            g.x = fmaf(hg, wg.x, g.x);
            g.y = fmaf(hg, wg.y, g.y);
            bv.x = fmaf(hb, wb.x, bv.x);
            bv.y = fmaf(hb, wb.y, bv.y);
        }
        float2 go = {1.f + g.x, 1.f + g.y};
        ((float2*)(gam + (size_t)i * D))[d2] = go;
        ((float2*)(bet + (size_t)i * D))[d2] = bv;
    }
    grid.sync();

    // ---------------- P4: gated-softmax + dot; block = (caption, 4-image group) ----------------
    {
        int cb = blk & 63, ig = blk >> 6;
        const float4* base = (const float4*)(cap + (size_t)cb * TCAP * D);
        float4 mu4 = ((const float4*)mu)[tid];
        float4 is4 = ((const float4*)istd)[tid];
        const float A = 14.4269504089f;     // 10 * log2(e)
        const float INV = 0.0693147180560f; // ln(2) / 10
        float a[4][4], c[4][4], sw[4][4], sxa[4][4];
#pragma unroll
        for (int k = 0; k < 4; ++k) {
            int i = ig * 4 + k;
            float4 g = ((const float4*)(gam + (size_t)i * D))[tid];
            float4 be = ((const float4*)(bet + (size_t)i * D))[tid];
            a[k][0] = A * g.x; a[k][1] = A * g.y; a[k][2] = A * g.z; a[k][3] = A * g.w;
            c[k][0] = A * (be.x - 6.f); c[k][1] = A * (be.y - 6.f);
            c[k][2] = A * (be.z - 6.f); c[k][3] = A * (be.w - 6.f);
#pragma unroll
            for (int ch = 0; ch < 4; ++ch) { sw[k][ch] = 0.f; sxa[k][ch] = 0.f; }
        }
#pragma unroll 4
        for (int t = 0; t < TIMG; ++t) {
            float4 cp = base[t * 256 + tid];
            float x[4];
            x[0] = (cp.x - mu4.x) * is4.x;
            x[1] = (cp.y - mu4.y) * is4.y;
            x[2] = (cp.z - mu4.z) * is4.z;
            x[3] = (cp.w - mu4.w) * is4.w;
#pragma unroll
            for (int k = 0; k < 4; ++k)
#pragma unroll
                for (int ch = 0; ch < 4; ++ch) {
                    float arg = fmaf(a[k][ch], x[ch], c[k][ch]);
                    float e = __builtin_amdgcn_exp2f(arg);
                    sw[k][ch] += e;
                    sxa[k][ch] = fmaf(e, arg, sxa[k][ch]);
                }
        }
        __syncthreads();   // smem handoff from P3 use
        float* smemS = smem;
        float* smemD = smem + 16;
#pragma unroll
        for (int k = 0; k < 4; ++k) {
            int i = ig * 4 + k;
            float4 iv = ((const float4*)(ivec + (size_t)i * D))[tid];
            float tv0 = fmaf(INV, sxa[k][0] / sw[k][0], 6.f);
            float tv1 = fmaf(INV, sxa[k][1] / sw[k][1], 6.f);
            float tv2 = fmaf(INV, sxa[k][2] / sw[k][2], 6.f);
            float tv3 = fmaf(INV, sxa[k][3] / sw[k][3], 6.f);
            float ss = tv0 * tv0 + tv1 * tv1 + tv2 * tv2 + tv3 * tv3;
            float sd = iv.x * tv0 + iv.y * tv1 + iv.z * tv2 + iv.w * tv3;
            for (int off = 32; off; off >>= 1) {
                ss += __shfl_xor(ss, off);
                sd += __shfl_xor(sd, off);
            }
            if (lane == 0) { smemS[wave * 4 + k] = ss; smemD[wave * 4 + k] = sd; }
        }
        __syncthreads();
        if (tid < 4) {
            float s = 0.f, d = 0.f;
#pragma unroll
            for (int w = 0; w < 4; ++w) { s += smemS[w * 4 + tid]; d += smemD[w * 4 + tid]; }
            out[(ig * 4 + tid) * BC + cb] = d * rsqrtf(s);
        }
    }
}

// =================== fallback kernels (round-5 proven path) ===================
__global__ __launch_bounds__(256) void k_pre(const float* __restrict__ img,
                                             const float* __restrict__ cap,
                                             const float* __restrict__ Wg1,
                                             const float* __restrict__ Wb1,
                                             float* __restrict__ repr,
                                             float* __restrict__ ivec,
                                             float* __restrict__ part,
                                             float* __restrict__ W1T) {
    int blk = blockIdx.x, tid = threadIdx.x;
    if (blk < 64) {
        int i = blk;
        const float4* base = (const float4*)(img + (size_t)i * TIMG * D);
        float4 s = {0.f, 0.f, 0.f, 0.f};
        for (int t = 0; t < TIMG; ++t) {
            float4 v = base[t * 256 + tid];
            s.x += v.x; s.y += v.y; s.z += v.z; s.w += v.w;
        }
        s.x *= (1.f / 36.f); s.y *= (1.f / 36.f); s.z *= (1.f / 36.f); s.w *= (1.f / 36.f);
        ((float4*)(repr + (size_t)i * D))[tid] = s;
        float local = s.x * s.x + s.y * s.y + s.z * s.z + s.w * s.w;
        for (int off = 32; off; off >>= 1) local += __shfl_xor(local, off);
        __shared__ float red[4];
        int wave = tid >> 6;
        if ((tid & 63) == 0) red[wave] = local;
        __syncthreads();
        float inv = rsqrtf(red[0] + red[1] + red[2] + red[3]);
        float4 o = {s.x * inv, s.y * inv, s.z * inv, s.w * inv};
        ((float4*)(ivec + (size_t)i * D))[tid] = o;
    } else if (blk < 128) {
        int b = blk - 64;
        const float4* base = (const float4*)(cap + (size_t)b * TCAP * D);
        float4 s = {0.f, 0.f, 0.f, 0.f}, ss = {0.f, 0.f, 0.f, 0.f};
        for (int t = 0; t < TIMG; ++t) {
            float4 v = base[t * 256 + tid];
            s.x += v.x; s.y += v.y; s.z += v.z; s.w += v.w;
            ss.x = fmaf(v.x, v.x, ss.x); ss.y = fmaf(v.y, v.y, ss.y);
            ss.z = fmaf(v.z, v.z, ss.z); ss.w = fmaf(v.w, v.w, ss.w);
        }
        ((float4*)(part + b * 2048))[tid] = s;
        ((float4*)(part + b * 2048 + 1024))[tid] = ss;
    } else {
        __shared__ float tile[64][65];
        int idx = blk - 128;
        int bx = idx & 15, by = (idx >> 4) & 1, bz = idx >> 5;
        const float* W = bz ? Wb1 : Wg1;
        int d0 = bx * 64, c0 = by * 64;
        int lane = tid & 63, w = tid >> 6;
#pragma unroll
        for (int k = 0; k < 16; ++k) {
            int dl = k * 4 + w;
            tile[dl][lane] = W[(size_t)(d0 + dl) * H + c0 + lane];
        }
        __syncthreads();
#pragma unroll
        for (int k = 0; k < 16; ++k) {
            int cl = k * 4 + w;
            W1T[(size_t)(bz * 128 + c0 + cl) * D + d0 + lane] = tile[lane][cl];
        }
    }
}

__global__ __launch_bounds__(256) void k_mid(const float* __restrict__ part,
                                             const float* __restrict__ repr,
                                             const float* __restrict__ W1T,
                                             const float* __restrict__ bg1,
                                             const float* __restrict__ bb1,
                                             float* __restrict__ mu,
                                             float* __restrict__ istd,
                                             float* __restrict__ hid) {
    int blk = blockIdx.x, tid = threadIdx.x;
    if (blk < 4) {
        int d = blk * 256 + tid;
        float s = 0.f, ss = 0.f;
        for (int g = 0; g < BC; ++g) {
            s += part[g * 2048 + d];
            ss += part[g * 2048 + 1024 + d];
        }
        const float invN = 1.f / 2304.f;
        float m = s * invN;
        float v = ss * invN - m * m;
        mu[d] = m;
        istd[d] = rsqrtf(v + 1e-5f);
    } else {
        int o = (blk - 4) * 4 + (tid >> 6);
        int lane = tid & 63;
        int i = o >> 8, c = o & 255;
        const float4* r = (const float4*)(repr + (size_t)i * D);
        const float4* w = (const float4*)(W1T + (size_t)c * D);
        float acc = 0.f;
#pragma unroll
        for (int k = 0; k < 4; ++k) {
            float4 rv = r[k * 64 + lane];
            float4 wv = w[k * 64 + lane];
            acc = fmaf(rv.x, wv.x, acc);
            acc = fmaf(rv.y, wv.y, acc);
            acc = fmaf(rv.z, wv.z, acc);
            acc = fmaf(rv.w, wv.w, acc);
        }
        for (int off = 32; off; off >>= 1) acc += __shfl_xor(acc, off);
        if (lane == 0) {
            float b = (c < 128) ? bg1[c] : bb1[c - 128];
            hid[o] = fmaxf(acc + b, 0.f);
        }
    }
}

__global__ __launch_bounds__(256) void k_out(const float* __restrict__ hid,
                                             const float* __restrict__ Wg2, const float* __restrict__ bg2,
                                             const float* __restrict__ Wb2, const float* __restrict__ bb2,
                                             float* __restrict__ gam, float* __restrict__ bet) {
    int i = blockIdx.x >> 1;
    int d2 = (blockIdx.x & 1) * 256 + threadIdx.x;
    __shared__ float h[256];
    h[threadIdx.x] = hid[i * 256 + threadIdx.x];
    __syncthreads();
    float2 g = ((const float2*)bg2)[d2];
    float2 bb = ((const float2*)bb2)[d2];
#pragma unroll 4
    for (int hh = 0; hh < H; ++hh) {
        float2 wg = ((const float2*)(Wg2 + (size_t)hh * D))[d2];
        float2 wb = ((const float2*)(Wb2 + (size_t)hh * D))[d2];
        float hg = h[hh], hb = h[128 + hh];
        g.x = fmaf(hg, wg.x, g.x);
        g.y = fmaf(hg, wg.y, g.y);
        bb.x = fmaf(hb, wb.x, bb.x);
        bb.y = fmaf(hb, wb.y, bb.y);
    }
    float2 go = {1.f + g.x, 1.f + g.y};
    ((float2*)(gam + (size_t)i * D))[d2] = go;
    ((float2*)(bet + (size_t)i * D))[d2] = bb;
}

__global__ __launch_bounds__(512) void k_main(const float* __restrict__ cap,
                                              const float* __restrict__ mu,
                                              const float* __restrict__ istd,
                                              const float* __restrict__ gam,
                                              const float* __restrict__ bet,
                                              const float* __restrict__ ivec,
                                              float* __restrict__ out) {
    int b = blockIdx.x, ig = blockIdx.y, tid = threadIdx.x;
    const float2* base = (const float2*)(cap + (size_t)b * TCAP * D);
    float2 mu2 = ((const float2*)mu)[tid];
    float2 is2 = ((const float2*)istd)[tid];
    const float A = 14.4269504089f;
    const float INV = 0.0693147180560f;
    float a0[8], a1[8], c0[8], c1[8];
    float sw0[8], sw1[8], sxa0[8], sxa1[8];
#pragma unroll
    for (int k = 0; k < 8; ++k) {
        int i = ig * 8 + k;
        float2 g = ((const float2*)(gam + (size_t)i * D))[tid];
        float2 be = ((const float2*)(bet + (size_t)i * D))[tid];
        a0[k] = A * g.x;
        a1[k] = A * g.y;
        c0[k] = A * (be.x - 6.f);
        c1[k] = A * (be.y - 6.f);
        sw0[k] = 0.f; sw1[k] = 0.f; sxa0[k] = 0.f; sxa1[k] = 0.f;
    }
#pragma unroll 4
    for (int t = 0; t < TIMG; ++t) {
        float2 cp = base[t * 512 + tid];
        float x0 = (cp.x - mu2.x) * is2.x;
        float x1 = (cp.y - mu2.y) * is2.y;
#pragma unroll
        for (int k = 0; k < 8; ++k) {
            float arg0 = fmaf(a0[k], x0, c0[k]);
            float e0 = __builtin_amdgcn_exp2f(arg0);
            sw0[k] += e0;
            sxa0[k] = fmaf(e0, arg0, sxa0[k]);
            float arg1 = fmaf(a1[k], x1, c1[k]);
            float e1 = __builtin_amdgcn_exp2f(arg1);
            sw1[k] += e1;
            sxa1[k] = fmaf(e1, arg1, sxa1[k]);
        }
    }
    __shared__ float redS[8][8], redD[8][8];
    int wave = tid >> 6;
#pragma unroll
    for (int k = 0; k < 8; ++k) {
        int i = ig * 8 + k;
        float2 iv = ((const float2*)(ivec + (size_t)i * D))[tid];
        float tv0 = fmaf(INV, sxa0[k] / sw0[k], 6.f);
        float tv1 = fmaf(INV, sxa1[k] / sw1[k], 6.f);
        float ss = tv0 * tv0 + tv1 * tv1;
        float sd = iv.x * tv0 + iv.y * tv1;
        for (int off = 32; off; off >>= 1) {
            ss += __shfl_xor(ss, off);
            sd += __shfl_xor(sd, off);
        }
        if ((tid & 63) == 0) { redS[k][wave] = ss; redD[k][wave] = sd; }
    }
    __syncthreads();
    if (tid < 64) {
        int k = tid >> 3, w = tid & 7;
        float s = redS[k][w], d = redD[k][w];
#pragma unroll
        for (int off = 1; off < 8; off <<= 1) {
            s += __shfl_xor(s, off);
            d += __shfl_xor(d, off);
        }
        if (w == 0) {
            int i = ig * 8 + k;
            out[i * BC + b] = d * rsqrtf(s);
        }
    }
}

extern "C" void kernel_launch(void* const* d_in, const int* in_sizes, int n_in,
                              void* d_out, int out_size, void* d_ws, size_t ws_size,
                              hipStream_t stream) {
    const float* img = (const float*)d_in[0];
    const float* cap = (const float*)d_in[1];
    // d_in[2] = lens (unused by the reference)
    const float* Wg1 = (const float*)d_in[3];
    const float* bg1 = (const float*)d_in[4];
    const float* Wg2 = (const float*)d_in[5];
    const float* bg2 = (const float*)d_in[6];
    const float* Wb1 = (const float*)d_in[7];
    const float* bb1 = (const float*)d_in[8];
    const float* Wb2 = (const float*)d_in[9];
    const float* bb2 = (const float*)d_in[10];

    float* ws = (float*)d_ws;
    float* repr = ws;                // 65536
    float* ivec = ws + 65536;        // 65536
    float* gam  = ws + 131072;       // 65536
    float* bet  = ws + 196608;       // 65536
    float* mu   = ws + 262144;       // 1024
    float* istd = ws + 263168;       // 1024
    float* part = ws + 264192;       // 131072
    float* W1T  = ws + 395264;       // 262144
    float* hid  = ws + 657408;       // 16384
    float* out = (float*)d_out;

    void* args[] = {
        (void*)&img, (void*)&cap,
        (void*)&Wg1, (void*)&bg1, (void*)&Wg2, (void*)&bg2,
        (void*)&Wb1, (void*)&bb1, (void*)&Wb2, (void*)&bb2,
        (void*)&repr, (void*)&ivec, (void*)&gam, (void*)&bet,
        (void*)&mu, (void*)&istd, (void*)&part, (void*)&W1T,
        (void*)&hid, (void*)&out
    };
    hipError_t e = hipLaunchCooperativeKernel((const void*)k_all, dim3(1024), dim3(256),
                                              args, 0, stream);
    if (e != hipSuccess) {
        (void)hipGetLastError();   // clear sticky error; use proven 4-kernel path
        k_pre<<<dim3(192), dim3(256), 0, stream>>>(img, cap, Wg1, Wb1, repr, ivec, part, W1T);
        k_mid<<<dim3(4100), dim3(256), 0, stream>>>(part, repr, W1T, bg1, bb1, mu, istd, hid);
        k_out<<<dim3(128), dim3(256), 0, stream>>>(hid, Wg2, bg2, Wb2, bb2, gam, bet);
        k_main<<<dim3(BC, 8), dim3(512), 0, stream>>>(cap, mu, istd, gam, bet, ivec, out);
    }
}

// Round 7
// 90.286 us; speedup vs baseline: 4.3872x; 4.3872x over previous
//
#include <hip/hip_runtime.h>
#include <hip/hip_bf16.h>

// Sizes (fixed by the reference)
#define BI 64
#define BC 64
#define TCAP 64
#define D 1024
#define H 128
#define TIMG 36

// ---------------- Kernel A: img stats | cap partial stats | W1 transpose ----------------
// grid 192 x 256:  blk<64: img   64<=blk<128: capstat   128<=blk: w1t
__global__ __launch_bounds__(256) void k_pre(const float* __restrict__ img,
                                             const float* __restrict__ cap,
                                             const float* __restrict__ Wg1,
                                             const float* __restrict__ Wb1,
                                             float* __restrict__ repr,
                                             float* __restrict__ ivec,
                                             float* __restrict__ part,
                                             float* __restrict__ W1T) {
    int blk = blockIdx.x, tid = threadIdx.x;
    if (blk < 64) {
        // ---- img_repr mean + l2-normalized img_vec (thread owns 4 channels) ----
        int i = blk;
        const float4* base = (const float4*)(img + (size_t)i * TIMG * D);
        float4 s = {0.f, 0.f, 0.f, 0.f};
        for (int t = 0; t < TIMG; ++t) {
            float4 v = base[t * 256 + tid];
            s.x += v.x; s.y += v.y; s.z += v.z; s.w += v.w;
        }
        s.x *= (1.f / 36.f); s.y *= (1.f / 36.f); s.z *= (1.f / 36.f); s.w *= (1.f / 36.f);
        ((float4*)(repr + (size_t)i * D))[tid] = s;
        float local = s.x * s.x + s.y * s.y + s.z * s.z + s.w * s.w;
        for (int off = 32; off; off >>= 1) local += __shfl_xor(local, off);
        __shared__ float red[4];
        int wave = tid >> 6;
        if ((tid & 63) == 0) red[wave] = local;
        __syncthreads();
        float inv = rsqrtf(red[0] + red[1] + red[2] + red[3]);
        float4 o = {s.x * inv, s.y * inv, s.z * inv, s.w * inv};
        ((float4*)(ivec + (size_t)i * D))[tid] = o;
    } else if (blk < 128) {
        // ---- per-channel partial sums over t<36 for one caption b (4 ch/thread) ----
        int b = blk - 64;
        const float4* base = (const float4*)(cap + (size_t)b * TCAP * D);
        float4 s = {0.f, 0.f, 0.f, 0.f}, ss = {0.f, 0.f, 0.f, 0.f};
        for (int t = 0; t < TIMG; ++t) {
            float4 v = base[t * 256 + tid];
            s.x += v.x; s.y += v.y; s.z += v.z; s.w += v.w;
            ss.x = fmaf(v.x, v.x, ss.x); ss.y = fmaf(v.y, v.y, ss.y);
            ss.z = fmaf(v.z, v.z, ss.z); ss.w = fmaf(v.w, v.w, ss.w);
        }
        ((float4*)(part + b * 2048))[tid] = s;
        ((float4*)(part + b * 2048 + 1024))[tid] = ss;
    } else {
        // ---- transpose+concat W1 -> W1T[256][1024] ----
        __shared__ float tile[64][65];
        int idx = blk - 128;
        int bx = idx & 15, by = (idx >> 4) & 1, bz = idx >> 5;
        const float* W = bz ? Wb1 : Wg1;
        int d0 = bx * 64, c0 = by * 64;
        int lane = tid & 63, w = tid >> 6;
#pragma unroll
        for (int k = 0; k < 16; ++k) {
            int dl = k * 4 + w;
            tile[dl][lane] = W[(size_t)(d0 + dl) * H + c0 + lane];
        }
        __syncthreads();
#pragma unroll
        for (int k = 0; k < 16; ++k) {
            int cl = k * 4 + w;
            W1T[(size_t)(bz * 128 + c0 + cl) * D + d0 + lane] = tile[lane][cl];
        }
    }
}

// ---------------- Kernel B: stat finalize | fused per-image MLP (hidden + layer2) ----------------
// grid 68 x 256: blk<4: mu/istd finalize   blk>=4: image i = blk-4
__global__ __launch_bounds__(256) void k_mlp(const float* __restrict__ part,
                                             const float* __restrict__ repr,
                                             const float* __restrict__ W1T,
                                             const float* __restrict__ bg1,
                                             const float* __restrict__ bb1,
                                             const float* __restrict__ Wg2, const float* __restrict__ bg2,
                                             const float* __restrict__ Wb2, const float* __restrict__ bb2,
                                             float* __restrict__ mu,
                                             float* __restrict__ istd,
                                             float* __restrict__ gam, float* __restrict__ bet) {
    int blk = blockIdx.x, tid = threadIdx.x;
    if (blk < 4) {
        if (blk > 0) return;   // single block does all 1024 channels (float4/thread)
        const float4* p4 = (const float4*)part;
        float4 s = {0.f, 0.f, 0.f, 0.f}, q = {0.f, 0.f, 0.f, 0.f};
        for (int g = 0; g < BC; ++g) {
            float4 a4 = p4[g * 512 + tid];
            float4 b4 = p4[g * 512 + 256 + tid];
            s.x += a4.x; s.y += a4.y; s.z += a4.z; s.w += a4.w;
            q.x += b4.x; q.y += b4.y; q.z += b4.z; q.w += b4.w;
        }
        const float invN = 1.f / 2304.f;
        float4 m = {s.x * invN, s.y * invN, s.z * invN, s.w * invN};
        float4 v = {q.x * invN - m.x * m.x, q.y * invN - m.y * m.y,
                    q.z * invN - m.z * m.z, q.w * invN - m.w * m.w};
        ((float4*)mu)[tid] = m;
        float4 ist = {rsqrtf(v.x + 1e-5f), rsqrtf(v.y + 1e-5f),
                      rsqrtf(v.z + 1e-5f), rsqrtf(v.w + 1e-5f)};
        ((float4*)istd)[tid] = ist;
        return;
    }
    int i = blk - 4;
    int lane = tid & 63, wave = tid >> 6;
    __shared__ float h[256];
    // ---- hidden layer: wave handles 64 consecutive c; repr fragment hoisted ----
    const float4* r4 = (const float4*)(repr + (size_t)i * D);
    float4 rv0 = r4[lane], rv1 = r4[64 + lane], rv2 = r4[128 + lane], rv3 = r4[192 + lane];
    for (int j = 0; j < 64; ++j) {
        int cc = wave * 64 + j;
        const float4* w4 = (const float4*)(W1T + (size_t)cc * D);
        float4 w0 = w4[lane], w1 = w4[64 + lane], w2 = w4[128 + lane], w3 = w4[192 + lane];
        float acc = 0.f;
        acc = fmaf(rv0.x, w0.x, acc); acc = fmaf(rv0.y, w0.y, acc);
        acc = fmaf(rv0.z, w0.z, acc); acc = fmaf(rv0.w, w0.w, acc);
        acc = fmaf(rv1.x, w1.x, acc); acc = fmaf(rv1.y, w1.y, acc);
        acc = fmaf(rv1.z, w1.z, acc); acc = fmaf(rv1.w, w1.w, acc);
        acc = fmaf(rv2.x, w2.x, acc); acc = fmaf(rv2.y, w2.y, acc);
        acc = fmaf(rv2.z, w2.z, acc); acc = fmaf(rv2.w, w2.w, acc);
        acc = fmaf(rv3.x, w3.x, acc); acc = fmaf(rv3.y, w3.y, acc);
        acc = fmaf(rv3.z, w3.z, acc); acc = fmaf(rv3.w, w3.w, acc);
        for (int off = 32; off; off >>= 1) acc += __shfl_xor(acc, off);
        if (lane == 0) {
            float b1v = (cc < 128) ? bg1[cc] : bb1[cc - 128];
            h[cc] = fmaxf(acc + b1v, 0.f);
        }
    }
    __syncthreads();
    // ---- layer 2: thread owns float4 d-slot tid ----
    float4 g = ((const float4*)bg2)[tid];
    float4 bv = ((const float4*)bb2)[tid];
#pragma unroll 4
    for (int hh = 0; hh < H; ++hh) {
        float hg = h[hh], hb = h[128 + hh];
        float4 wg = ((const float4*)(Wg2 + (size_t)hh * D))[tid];
        float4 wb = ((const float4*)(Wb2 + (size_t)hh * D))[tid];
        g.x = fmaf(hg, wg.x, g.x); g.y = fmaf(hg, wg.y, g.y);
        g.z = fmaf(hg, wg.z, g.z); g.w = fmaf(hg, wg.w, g.w);
        bv.x = fmaf(hb, wb.x, bv.x); bv.y = fmaf(hb, wb.y, bv.y);
        bv.z = fmaf(hb, wb.z, bv.z); bv.w = fmaf(hb, wb.w, bv.w);
    }
    float4 go = {1.f + g.x, 1.f + g.y, 1.f + g.z, 1.f + g.w};
    ((float4*)(gam + (size_t)i * D))[tid] = go;
    ((float4*)(bet + (size_t)i * D))[tid] = bv;
}

// ---------------- Kernel C: main gated-softmax + dot ----------------
// grid (b=64, ig=8) x 512; thread owns adjacent channel pair (2tid, 2tid+1)
__global__ __launch_bounds__(512) void k_main(const float* __restrict__ cap,
                                              const float* __restrict__ mu,
                                              const float* __restrict__ istd,
                                              const float* __restrict__ gam,
                                              const float* __restrict__ bet,
                                              const float* __restrict__ ivec,
                                              float* __restrict__ out) {
    int b = blockIdx.x, ig = blockIdx.y, tid = threadIdx.x;
    const float2* base = (const float2*)(cap + (size_t)b * TCAP * D);
    float2 mu2 = ((const float2*)mu)[tid];
    float2 is2 = ((const float2*)istd)[tid];
    const float A = 14.4269504089f;     // 10 * log2(e)
    const float INV = 0.0693147180560f; // ln(2) / 10

    float a0[8], a1[8], c0[8], c1[8];
    float sw0[8], sw1[8], sxa0[8], sxa1[8];
#pragma unroll
    for (int k = 0; k < 8; ++k) {
        int i = ig * 8 + k;
        float2 g = ((const float2*)(gam + (size_t)i * D))[tid];
        float2 be = ((const float2*)(bet + (size_t)i * D))[tid];
        a0[k] = A * g.x;
        a1[k] = A * g.y;
        c0[k] = A * (be.x - 6.f);
        c1[k] = A * (be.y - 6.f);
        sw0[k] = 0.f; sw1[k] = 0.f; sxa0[k] = 0.f; sxa1[k] = 0.f;
    }
#pragma unroll 4
    for (int t = 0; t < TIMG; ++t) {
        float2 cp = base[t * 512 + tid];
        float x0 = (cp.x - mu2.x) * is2.x;
        float x1 = (cp.y - mu2.y) * is2.y;
#pragma unroll
        for (int k = 0; k < 8; ++k) {
            float arg0 = fmaf(a0[k], x0, c0[k]);
            float e0 = __builtin_amdgcn_exp2f(arg0);
            sw0[k] += e0;
            sxa0[k] = fmaf(e0, arg0, sxa0[k]);
            float arg1 = fmaf(a1[k], x1, c1[k]);
            float e1 = __builtin_amdgcn_exp2f(arg1);
            sw1[k] += e1;
            sxa1[k] = fmaf(e1, arg1, sxa1[k]);
        }
    }
    __shared__ float redS[8][8], redD[8][8];
    int wave = tid >> 6;
#pragma unroll
    for (int k = 0; k < 8; ++k) {
        int i = ig * 8 + k;
        float2 iv = ((const float2*)(ivec + (size_t)i * D))[tid];
        // tv = INV * (sxa/sw) + 6   (since txt = arg*INV + 6)
        float tv0 = fmaf(INV, sxa0[k] / sw0[k], 6.f);
        float tv1 = fmaf(INV, sxa1[k] / sw1[k], 6.f);
        float ss = tv0 * tv0 + tv1 * tv1;
        float sd = iv.x * tv0 + iv.y * tv1;
        for (int off = 32; off; off >>= 1) {
            ss += __shfl_xor(ss, off);
            sd += __shfl_xor(sd, off);
        }
        if ((tid & 63) == 0) { redS[k][wave] = ss; redD[k][wave] = sd; }
    }
    __syncthreads();
    if (tid < 64) {
        int k = tid >> 3, w = tid & 7;
        float s = redS[k][w], d = redD[k][w];
#pragma unroll
        for (int off = 1; off < 8; off <<= 1) {
            s += __shfl_xor(s, off);
            d += __shfl_xor(d, off);
        }
        if (w == 0) {
            int i = ig * 8 + k;
            out[i * BC + b] = d * rsqrtf(s);
        }
    }
}

extern "C" void kernel_launch(void* const* d_in, const int* in_sizes, int n_in,
                              void* d_out, int out_size, void* d_ws, size_t ws_size,
                              hipStream_t stream) {
    const float* img = (const float*)d_in[0];
    const float* cap = (const float*)d_in[1];
    // d_in[2] = lens (unused by the reference)
    const float* Wg1 = (const float*)d_in[3];
    const float* bg1 = (const float*)d_in[4];
    const float* Wg2 = (const float*)d_in[5];
    const float* bg2 = (const float*)d_in[6];
    const float* Wb1 = (const float*)d_in[7];
    const float* bb1 = (const float*)d_in[8];
    const float* Wb2 = (const float*)d_in[9];
    const float* bb2 = (const float*)d_in[10];

    float* ws = (float*)d_ws;
    float* repr = ws;                // 65536
    float* ivec = ws + 65536;        // 65536
    float* gam  = ws + 131072;       // 65536
    float* bet  = ws + 196608;       // 65536
    float* mu   = ws + 262144;       // 1024
    float* istd = ws + 263168;       // 1024
    float* part = ws + 264192;       // 131072
    float* W1T  = ws + 395264;       // 262144
    float* out = (float*)d_out;

    k_pre<<<dim3(192), dim3(256), 0, stream>>>(img, cap, Wg1, Wb1, repr, ivec, part, W1T);
    k_mlp<<<dim3(68), dim3(256), 0, stream>>>(part, repr, W1T, bg1, bb1,
                                              Wg2, bg2, Wb2, bb2, mu, istd, gam, bet);
    k_main<<<dim3(BC, 8), dim3(512), 0, stream>>>(cap, mu, istd, gam, bet, ivec, out);
}

// Round 8
// 55.957 us; speedup vs baseline: 7.0786x; 1.6135x over previous
//
#include <hip/hip_runtime.h>
#include <hip/hip_bf16.h>

// Sizes (fixed by the reference)
#define BI 64
#define BC 64
#define TCAP 64
#define D 1024
#define H 128
#define TIMG 36

// ---------------- Kernel A: img stats | cap partial stats | W1 transpose ----------------
// grid 192 x 256:  blk<64: img   64<=blk<128: capstat   128<=blk: w1t
__global__ __launch_bounds__(256) void k_pre(const float* __restrict__ img,
                                             const float* __restrict__ cap,
                                             const float* __restrict__ Wg1,
                                             const float* __restrict__ Wb1,
                                             float* __restrict__ repr,
                                             float* __restrict__ ivec,
                                             float* __restrict__ part,
                                             float* __restrict__ W1T) {
    int blk = blockIdx.x, tid = threadIdx.x;
    if (blk < 64) {
        // ---- img_repr mean + l2-normalized img_vec (thread owns 4 channels) ----
        int i = blk;
        const float4* base = (const float4*)(img + (size_t)i * TIMG * D);
        float4 s = {0.f, 0.f, 0.f, 0.f};
        for (int t = 0; t < TIMG; ++t) {
            float4 v = base[t * 256 + tid];
            s.x += v.x; s.y += v.y; s.z += v.z; s.w += v.w;
        }
        s.x *= (1.f / 36.f); s.y *= (1.f / 36.f); s.z *= (1.f / 36.f); s.w *= (1.f / 36.f);
        ((float4*)(repr + (size_t)i * D))[tid] = s;
        float local = s.x * s.x + s.y * s.y + s.z * s.z + s.w * s.w;
        for (int off = 32; off; off >>= 1) local += __shfl_xor(local, off);
        __shared__ float red[4];
        int wave = tid >> 6;
        if ((tid & 63) == 0) red[wave] = local;
        __syncthreads();
        float inv = rsqrtf(red[0] + red[1] + red[2] + red[3]);
        float4 o = {s.x * inv, s.y * inv, s.z * inv, s.w * inv};
        ((float4*)(ivec + (size_t)i * D))[tid] = o;
    } else if (blk < 128) {
        // ---- per-channel partial sums over t<36 for one caption b (4 ch/thread) ----
        int b = blk - 64;
        const float4* base = (const float4*)(cap + (size_t)b * TCAP * D);
        float4 s = {0.f, 0.f, 0.f, 0.f}, ss = {0.f, 0.f, 0.f, 0.f};
        for (int t = 0; t < TIMG; ++t) {
            float4 v = base[t * 256 + tid];
            s.x += v.x; s.y += v.y; s.z += v.z; s.w += v.w;
            ss.x = fmaf(v.x, v.x, ss.x); ss.y = fmaf(v.y, v.y, ss.y);
            ss.z = fmaf(v.z, v.z, ss.z); ss.w = fmaf(v.w, v.w, ss.w);
        }
        ((float4*)(part + b * 2048))[tid] = s;
        ((float4*)(part + b * 2048 + 1024))[tid] = ss;
    } else {
        // ---- transpose+concat W1 -> W1T[256][1024] ----
        __shared__ float tile[64][65];
        int idx = blk - 128;
        int bx = idx & 15, by = (idx >> 4) & 1, bz = idx >> 5;
        const float* W = bz ? Wb1 : Wg1;
        int d0 = bx * 64, c0 = by * 64;
        int lane = tid & 63, w = tid >> 6;
#pragma unroll
        for (int k = 0; k < 16; ++k) {
            int dl = k * 4 + w;
            tile[dl][lane] = W[(size_t)(d0 + dl) * H + c0 + lane];
        }
        __syncthreads();
#pragma unroll
        for (int k = 0; k < 16; ++k) {
            int cl = k * 4 + w;
            W1T[(size_t)(bz * 128 + c0 + cl) * D + d0 + lane] = tile[lane][cl];
        }
    }
}

// ---------------- Kernel B: stat finalize | hidden layer ----------------
// grid 4100 x 256: blk<4: mu/istd   else: one wave per (i,c) hidden output
__global__ __launch_bounds__(256) void k_mid(const float* __restrict__ part,
                                             const float* __restrict__ repr,
                                             const float* __restrict__ W1T,
                                             const float* __restrict__ bg1,
                                             const float* __restrict__ bb1,
                                             float* __restrict__ mu,
                                             float* __restrict__ istd,
                                             float* __restrict__ hid) {
    int blk = blockIdx.x, tid = threadIdx.x;
    if (blk < 4) {
        int d = blk * 256 + tid;
        float s = 0.f, ss = 0.f;
        for (int g = 0; g < BC; ++g) {
            s += part[g * 2048 + d];
            ss += part[g * 2048 + 1024 + d];
        }
        const float invN = 1.f / 2304.f;
        float m = s * invN;
        float v = ss * invN - m * m;
        mu[d] = m;
        istd[d] = rsqrtf(v + 1e-5f);
    } else {
        int o = (blk - 4) * 4 + (tid >> 6);
        int lane = tid & 63;
        int i = o >> 8, c = o & 255;
        const float4* r = (const float4*)(repr + (size_t)i * D);
        const float4* w = (const float4*)(W1T + (size_t)c * D);
        float acc = 0.f;
#pragma unroll
        for (int k = 0; k < 4; ++k) {
            float4 rv = r[k * 64 + lane];
            float4 wv = w[k * 64 + lane];
            acc = fmaf(rv.x, wv.x, acc);
            acc = fmaf(rv.y, wv.y, acc);
            acc = fmaf(rv.z, wv.z, acc);
            acc = fmaf(rv.w, wv.w, acc);
        }
        for (int off = 32; off; off >>= 1) acc += __shfl_xor(acc, off);
        if (lane == 0) {
            float b = (c < 128) ? bg1[c] : bb1[c - 128];
            hid[o] = fmaxf(acc + b, 0.f);
        }
    }
}

// ---------------- Kernel C: second MLP layer -> gam, bet ----------------
// grid 256 x 128: i = blk>>2, float2 slot d2 = (blk&3)*128 + tid
__global__ __launch_bounds__(128) void k_out(const float* __restrict__ hid,
                                             const float* __restrict__ Wg2, const float* __restrict__ bg2,
                                             const float* __restrict__ Wb2, const float* __restrict__ bb2,
                                             float* __restrict__ gam, float* __restrict__ bet) {
    int i = blockIdx.x >> 2;
    int d2 = (blockIdx.x & 3) * 128 + threadIdx.x;
    __shared__ float h[256];
    h[threadIdx.x] = hid[i * 256 + threadIdx.x];
    h[128 + threadIdx.x] = hid[i * 256 + 128 + threadIdx.x];
    __syncthreads();
    float2 g = ((const float2*)bg2)[d2];
    float2 bb = ((const float2*)bb2)[d2];
#pragma unroll 4
    for (int hh = 0; hh < H; ++hh) {
        float2 wg = ((const float2*)(Wg2 + (size_t)hh * D))[d2];
        float2 wb = ((const float2*)(Wb2 + (size_t)hh * D))[d2];
        float hg = h[hh], hb = h[128 + hh];
        g.x = fmaf(hg, wg.x, g.x);
        g.y = fmaf(hg, wg.y, g.y);
        bb.x = fmaf(hb, wb.x, bb.x);
        bb.y = fmaf(hb, wb.y, bb.y);
    }
    float2 go = {1.f + g.x, 1.f + g.y};
    ((float2*)(gam + (size_t)i * D))[d2] = go;
    ((float2*)(bet + (size_t)i * D))[d2] = bb;
}

// ---------------- Kernel D: main gated-softmax + dot ----------------
// grid (b=64, ig=4) x 512; thread owns channel pair (2tid, 2tid+1); 16 images/block
__global__ __launch_bounds__(512, 1) void k_main(const float* __restrict__ cap,
                                                 const float* __restrict__ mu,
                                                 const float* __restrict__ istd,
                                                 const float* __restrict__ gam,
                                                 const float* __restrict__ bet,
                                                 const float* __restrict__ ivec,
                                                 float* __restrict__ out) {
    int b = blockIdx.x, ig = blockIdx.y, tid = threadIdx.x;
    const float2* base = (const float2*)(cap + (size_t)b * TCAP * D);
    float2 mu2 = ((const float2*)mu)[tid];
    float2 is2 = ((const float2*)istd)[tid];
    const float A = 14.4269504089f;     // 10 * log2(e)
    const float INV = 0.0693147180560f; // ln(2) / 10

    float a0[16], a1[16], c0[16], c1[16];
    float sw0[16], sw1[16], sxa0[16], sxa1[16];
#pragma unroll
    for (int k = 0; k < 16; ++k) {
        int i = ig * 16 + k;
        float2 g = ((const float2*)(gam + (size_t)i * D))[tid];
        float2 be = ((const float2*)(bet + (size_t)i * D))[tid];
        a0[k] = A * g.x;
        a1[k] = A * g.y;
        c0[k] = A * (be.x - 6.f);
        c1[k] = A * (be.y - 6.f);
        sw0[k] = 0.f; sw1[k] = 0.f; sxa0[k] = 0.f; sxa1[k] = 0.f;
    }
#pragma unroll 2
    for (int t = 0; t < TIMG; ++t) {
        float2 cp = base[t * 512 + tid];
        float x0 = (cp.x - mu2.x) * is2.x;
        float x1 = (cp.y - mu2.y) * is2.y;
#pragma unroll
        for (int k = 0; k < 16; ++k) {
            float arg0 = fmaf(a0[k], x0, c0[k]);
            float e0 = __builtin_amdgcn_exp2f(arg0);
            sw0[k] += e0;
            sxa0[k] = fmaf(e0, arg0, sxa0[k]);
            float arg1 = fmaf(a1[k], x1, c1[k]);
            float e1 = __builtin_amdgcn_exp2f(arg1);
            sw1[k] += e1;
            sxa1[k] = fmaf(e1, arg1, sxa1[k]);
        }
    }
    __shared__ float redS[16][8], redD[16][8];
    int wave = tid >> 6;
#pragma unroll
    for (int k = 0; k < 16; ++k) {
        int i = ig * 16 + k;
        float2 iv = ((const float2*)(ivec + (size_t)i * D))[tid];
        // tv = INV * (sxa/sw) + 6   (since txt = arg*INV + 6)
        float tv0 = fmaf(INV, sxa0[k] / sw0[k], 6.f);
        float tv1 = fmaf(INV, sxa1[k] / sw1[k], 6.f);
        float ss = tv0 * tv0 + tv1 * tv1;
        float sd = iv.x * tv0 + iv.y * tv1;
        for (int off = 32; off; off >>= 1) {
            ss += __shfl_xor(ss, off);
            sd += __shfl_xor(sd, off);
        }
        if ((tid & 63) == 0) { redS[k][wave] = ss; redD[k][wave] = sd; }
    }
    __syncthreads();
    if (tid < 128) {
        int k = tid >> 3, w = tid & 7;   // groups of 8 lanes, wave-aligned
        float s = redS[k][w], d = redD[k][w];
#pragma unroll
        for (int off = 1; off < 8; off <<= 1) {
            s += __shfl_xor(s, off);
            d += __shfl_xor(d, off);
        }
        if (w == 0) {
            int i = ig * 16 + k;
            out[i * BC + b] = d * rsqrtf(s);
        }
    }
}

extern "C" void kernel_launch(void* const* d_in, const int* in_sizes, int n_in,
                              void* d_out, int out_size, void* d_ws, size_t ws_size,
                              hipStream_t stream) {
    const float* img = (const float*)d_in[0];
    const float* cap = (const float*)d_in[1];
    // d_in[2] = lens (unused by the reference)
    const float* Wg1 = (const float*)d_in[3];
    const float* bg1 = (const float*)d_in[4];
    const float* Wg2 = (const float*)d_in[5];
    const float* bg2 = (const float*)d_in[6];
    const float* Wb1 = (const float*)d_in[7];
    const float* bb1 = (const float*)d_in[8];
    const float* Wb2 = (const float*)d_in[9];
    const float* bb2 = (const float*)d_in[10];

    float* ws = (float*)d_ws;
    float* repr = ws;                // 65536
    float* ivec = ws + 65536;        // 65536
    float* gam  = ws + 131072;       // 65536
    float* bet  = ws + 196608;       // 65536
    float* mu   = ws + 262144;       // 1024
    float* istd = ws + 263168;       // 1024
    float* part = ws + 264192;       // 131072
    float* W1T  = ws + 395264;       // 262144
    float* hid  = ws + 657408;       // 16384
    float* out = (float*)d_out;

    k_pre<<<dim3(192), dim3(256), 0, stream>>>(img, cap, Wg1, Wb1, repr, ivec, part, W1T);
    k_mid<<<dim3(4100), dim3(256), 0, stream>>>(part, repr, W1T, bg1, bb1, mu, istd, hid);
    k_out<<<dim3(256), dim3(128), 0, stream>>>(hid, Wg2, bg2, Wb2, bb2, gam, bet);
    k_main<<<dim3(BC, 4), dim3(512), 0, stream>>>(cap, mu, istd, gam, bet, ivec, out);
}